// Round 1
// baseline (75.858 us; speedup 1.0000x reference)
//
#include <hip/hip_runtime.h>
#include <cstddef>
#include <cstdint>

#define EMB   256
#define TWOD  512
#define NREL  128
#define BATCH 4096
#define LOG_SQRT_2PI 0.9189385332046727f

typedef __bf16          bf16x8  __attribute__((ext_vector_type(8)));
typedef unsigned short  u16x8   __attribute__((ext_vector_type(8)));
typedef float           f32x4   __attribute__((ext_vector_type(4)));

__device__ __forceinline__ unsigned short f2bf(float f) {
    unsigned u = __builtin_bit_cast(unsigned, f);
    u = (u + 0x7FFFu + ((u >> 16) & 1u)) >> 16;
    return (unsigned short)u;
}

__device__ __forceinline__ bf16x8 pack8(float4 a, float4 b) {
    u16x8 u;
    u[0] = f2bf(a.x); u[1] = f2bf(a.y); u[2] = f2bf(a.z); u[3] = f2bf(a.w);
    u[4] = f2bf(b.x); u[5] = f2bf(b.y); u[6] = f2bf(b.z); u[7] = f2bf(b.w);
    return __builtin_bit_cast(bf16x8, u);
}

// ---------------------------------------------------------------------------
// Single fused kernel, zero workspace.
// Grid 256 blocks (1/CU): blockIdx = rb (64-row block, low 6 bits) x rg
// (32-relation group, high 2 bits) so the 4 blocks sharing rows land on the
// same XCD (x reused in its L2).
//
// Phase 1 (staging): 256 threads compute the block's 32-relation B-strip
//   c[r,k] = mu/sigma^2, a[r,k] = -0.5/sigma^2 (bf16) straight from mu/sigma
//   into 64 KB LDS, layout [k8(64)][c|a][r(32)][8shorts]:
//     - global reads: 8-lane r-groups read 256 B contiguous (coalesced)
//     - ds_write_b128: lane group g -> banks [4g,4g+4) = even 8 words/bank,
//       conflict-free
//   cst[r] = sum_k(-.5 mu^2/s^2 - log s - C) + 512*prior via 8-lane
//   __shfl_down reduce -> 32 floats in static LDS.
// One __syncthreads.
// Phase 2: proven MFMA loop (identical math/layout to the 72 us version),
//   B-frags now ds_read_b128 (16 B/lane contiguous, conflict-free) instead of
//   global: per wave 16 frags x {c,a} x {2 n-strips}, 4 indep acc chains.
//   All 4 waves share ONE B-strip -> 4x less B traffic than before.
// ---------------------------------------------------------------------------
__global__ __launch_bounds__(256, 1) void nb_one(
    const float* __restrict__ sbjs, const float* __restrict__ objs,
    const float* __restrict__ mus,  const float* __restrict__ sigmas,
    const float* __restrict__ priors, float* __restrict__ out)
{
    extern __shared__ unsigned short Wl[];   // dynamic 64 KB: [k8][sel][r][8]
    __shared__ float cstl[32];

    const int tid = threadIdx.x;
    const int rb  = blockIdx.x & 63;   // rows [rb*64, rb*64+64)
    const int rg  = blockIdx.x >> 6;   // relations [rg*32, rg*32+32)

    // ---- Phase 1: stage B + cst ----
    {
        const int rl = tid >> 3;           // local relation 0..31
        const int j0 = tid & 7;           // k8 stride-8 phase
        const int R  = rg * 32 + rl;
        const float* mp = mus    + (size_t)R * TWOD;
        const float* sp = sigmas + (size_t)R * TWOD;
        float esum = 0.0f;
        #pragma unroll
        for (int j = 0; j < 8; j++) {
            const int k8 = j * 8 + j0;    // lanes of an r-group cover 256 B contig
            const float4 m0 = *(const float4*)(mp + k8 * 8);
            const float4 m1 = *(const float4*)(mp + k8 * 8 + 4);
            const float4 s0 = *(const float4*)(sp + k8 * 8);
            const float4 s1 = *(const float4*)(sp + k8 * 8 + 4);
            const float mu[8] = {m0.x, m0.y, m0.z, m0.w, m1.x, m1.y, m1.z, m1.w};
            const float sg[8] = {s0.x, s0.y, s0.z, s0.w, s1.x, s1.y, s1.z, s1.w};
            u16x8 pc, pa;
            #pragma unroll
            for (int i = 0; i < 8; i++) {
                const float inv2 = 1.0f / (sg[i] * sg[i]);
                pc[i] = f2bf(mu[i] * inv2);
                pa[i] = f2bf(-0.5f * inv2);
                esum += -0.5f * mu[i] * mu[i] * inv2 - __logf(sg[i]) - LOG_SQRT_2PI;
            }
            unsigned short* w = Wl + k8 * 512 + rl * 8;   // plane=512 shorts
            *(u16x8*)(w)       = pc;                       // sel=c at +0
            *(u16x8*)(w + 256) = pa;                       // sel=a at +512 B
        }
        esum += __shfl_down(esum, 4, 64);
        esum += __shfl_down(esum, 2, 64);
        esum += __shfl_down(esum, 1, 64);
        if (j0 == 0) cstl[rl] = esum + priors[R] * (float)TWOD;
    }

    // ---- A-frags: x and x^2, bf16-packed (before barrier: overlaps staging) ----
    const int wv   = tid >> 6;
    const int lane = tid & 63;
    const int m16  = lane & 15;
    const int quad = lane >> 4;
    const int b0   = rb * 64 + wv * 16;
    const int row  = b0 + m16;

    bf16x8 ax[16], ax2[16];
    #pragma unroll
    for (int fi = 0; fi < 16; fi++) {
        const int col = fi * 32 + quad * 8;            // compile-time per fi
        const float* p = (col < EMB)
            ? (sbjs + (size_t)row * EMB + col)
            : (objs + (size_t)row * EMB + (col - EMB));
        const float4 v0 = *(const float4*)p;
        const float4 v1 = *(const float4*)(p + 4);
        ax[fi] = pack8(v0, v1);
        const float4 q0 = {v0.x * v0.x, v0.y * v0.y, v0.z * v0.z, v0.w * v0.w};
        const float4 q1 = {v1.x * v1.x, v1.y * v1.y, v1.z * v1.z, v1.w * v1.w};
        ax2[fi] = pack8(q0, q1);
    }

    __syncthreads();

    // ---- Phase 2: MFMA loop, B from LDS ----
    f32x4 accc[2], acca[2];
    accc[0] = (f32x4)0.0f; accc[1] = (f32x4)0.0f;
    acca[0] = (f32x4)0.0f; acca[1] = (f32x4)0.0f;

    // B-frag (fi, quad): plane k8 = fi*4+quad, local rel r = nt*16+m16.
    // shorts: plane*512 + sel*256 + r*8 -> 16 B/lane contiguous per 16 lanes.
    const unsigned short* wbase = Wl + quad * 512 + m16 * 8;
    #pragma unroll
    for (int fi = 0; fi < 16; fi++) {
        const unsigned short* wp = wbase + fi * 4 * 512;
        const bf16x8 bc0 = *(const bf16x8*)(wp);          // c, r = m16
        const bf16x8 bc1 = *(const bf16x8*)(wp + 128);    // c, r = 16+m16
        const bf16x8 ba0 = *(const bf16x8*)(wp + 256);    // a, r = m16
        const bf16x8 ba1 = *(const bf16x8*)(wp + 384);    // a, r = 16+m16
        accc[0] = __builtin_amdgcn_mfma_f32_16x16x32_bf16(ax [fi], bc0, accc[0], 0, 0, 0);
        acca[0] = __builtin_amdgcn_mfma_f32_16x16x32_bf16(ax2[fi], ba0, acca[0], 0, 0, 0);
        accc[1] = __builtin_amdgcn_mfma_f32_16x16x32_bf16(ax [fi], bc1, accc[1], 0, 0, 0);
        acca[1] = __builtin_amdgcn_mfma_f32_16x16x32_bf16(ax2[fi], ba1, acca[1], 0, 0, 0);
    }

    // ---- epilogue: C layout col(r)=lane&15, row(b)=quad*4+reg ----
    #pragma unroll
    for (int nt = 0; nt < 2; nt++) {
        const int rl = nt * 16 + m16;
        const int R  = rg * 32 + rl;
        const float ca = cstl[rl];
        #pragma unroll
        for (int reg = 0; reg < 4; reg++)
            out[(size_t)(b0 + quad * 4 + reg) * NREL + R] =
                accc[nt][reg] + acca[nt][reg] + ca;
    }
}

extern "C" void kernel_launch(void* const* d_in, const int* in_sizes, int n_in,
                              void* d_out, int out_size, void* d_ws, size_t ws_size,
                              hipStream_t stream)
{
    const float* sbjs   = (const float*)d_in[0];
    const float* objs   = (const float*)d_in[1];
    const float* mus    = (const float*)d_in[2];
    const float* sigmas = (const float*)d_in[3];
    const float* priors = (const float*)d_in[4];
    float* out = (float*)d_out;

    (void)d_ws; (void)ws_size;   // zero-workspace path: single fused kernel

    nb_one<<<256, 256, 64 << 10, stream>>>(sbjs, objs, mus, sigmas, priors, out);
}